// Round 2
// baseline (483.049 us; speedup 1.0000x reference)
//
#include <hip/hip_runtime.h>
#include <cstddef>
#include <cstdint>

#define BATCH 16
#define NFULL 896   // 512 real + 384 pad
#define NREAL 512
#define NPAD  384
#define DIM   256

// ---------------------------------------------------------------------------
// row inverse-norms for f1=concat(x1,x3) and f2=concat(x2,x4)
__global__ __launch_bounds__(256) void norm_kernel(
    const float* __restrict__ x1, const float* __restrict__ x3,
    const float* __restrict__ x2, const float* __restrict__ x4,
    float* __restrict__ invn1, float* __restrict__ invn2)
{
    const int w = threadIdx.x >> 6, lane = threadIdx.x & 63;
    const int rg = blockIdx.x * 4 + w;            // 0 .. 2*B*NFULL-1
    const int side = rg / (BATCH * NFULL);
    const int rem  = rg - side * (BATCH * NFULL);
    const int b = rem / NFULL, r = rem % NFULL;
    const float* src;
    if (side == 0)
        src = (r < NREAL) ? x1 + ((size_t)b * NREAL + r) * DIM
                          : x3 + ((size_t)b * NPAD + (r - NREAL)) * DIM;
    else
        src = (r < NREAL) ? x2 + ((size_t)b * NREAL + r) * DIM
                          : x4 + ((size_t)b * NPAD + (r - NREAL)) * DIM;
    float4 v = ((const float4*)src)[lane];
    float ss = v.x*v.x + v.y*v.y + v.z*v.z + v.w*v.w;
    #pragma unroll
    for (int m = 1; m < 64; m <<= 1) ss += __shfl_xor(ss, m);
    if (lane == 0)
        (side == 0 ? invn1 : invn2)[b * NFULL + r] = 1.0f / fmaxf(sqrtf(ss), 1e-12f);
}

// ---------------------------------------------------------------------------
// S = exp(10 * f1n @ f2n^T) over full 896x896; accumulate row/col sums;
// store S only on the 512x512 real block.
__global__ __launch_bounds__(256) void gram_kernel(
    const float* __restrict__ x1, const float* __restrict__ x3,
    const float* __restrict__ x2, const float* __restrict__ x4,
    const float* __restrict__ invn1, const float* __restrict__ invn2,
    float* __restrict__ S, float* __restrict__ rowsum, float* __restrict__ colsum)
{
    const int b  = blockIdx.z;
    const int i0 = blockIdx.y * 64;
    const int j0 = blockIdx.x * 64;
    __shared__ float As[64][68];   // pad 68 -> 16B-aligned rows, clean banks
    __shared__ float Bs[64][68];
    __shared__ float rsh[64], csh[64];
    const int t = threadIdx.x;
    const int tx = t & 15, ty = t >> 4;
    if (t < 64) { rsh[t] = 0.f; csh[t] = 0.f; }
    float acc[4][4] = {};
    const int lk = t & 63, r4 = t >> 6;

    for (int kc = 0; kc < DIM; kc += 64) {
        __syncthreads();
        #pragma unroll
        for (int rr = 0; rr < 64; rr += 4) {
            const int r = rr + r4;
            const int gi = i0 + r;
            const float* pa = (gi < NREAL) ? x1 + ((size_t)b * NREAL + gi) * DIM
                                           : x3 + ((size_t)b * NPAD + (gi - NREAL)) * DIM;
            As[r][lk] = pa[kc + lk] * invn1[b * NFULL + gi];
            const int gj = j0 + r;
            const float* pb = (gj < NREAL) ? x2 + ((size_t)b * NREAL + gj) * DIM
                                           : x4 + ((size_t)b * NPAD + (gj - NREAL)) * DIM;
            Bs[r][lk] = pb[kc + lk] * invn2[b * NFULL + gj];
        }
        __syncthreads();
        #pragma unroll
        for (int k = 0; k < 64; k += 4) {
            float4 av[4], bv[4];
            #pragma unroll
            for (int u = 0; u < 4; ++u) av[u] = *(const float4*)&As[ty + 16*u][k];
            #pragma unroll
            for (int u = 0; u < 4; ++u) bv[u] = *(const float4*)&Bs[tx + 16*u][k];
            #pragma unroll
            for (int u = 0; u < 4; ++u)
                #pragma unroll
                for (int v = 0; v < 4; ++v) {
                    acc[u][v] += av[u].x * bv[v].x;
                    acc[u][v] += av[u].y * bv[v].y;
                    acc[u][v] += av[u].z * bv[v].z;
                    acc[u][v] += av[u].w * bv[v].w;
                }
        }
    }

    float rpart[4] = {}, cpart[4] = {};
    const bool store = (i0 < NREAL) && (j0 < NREAL);
    #pragma unroll
    for (int u = 0; u < 4; ++u)
        #pragma unroll
        for (int v = 0; v < 4; ++v) {
            const float s = __expf(10.0f * acc[u][v]);
            rpart[u] += s;
            cpart[v] += s;
            if (store) {
                const int i = i0 + ty + 16*u, j = j0 + tx + 16*v;
                S[((size_t)b * NREAL + i) * NREAL + j] = s;
            }
        }
    #pragma unroll
    for (int u = 0; u < 4; ++u) atomicAdd(&rsh[ty + 16*u], rpart[u]);
    #pragma unroll
    for (int v = 0; v < 4; ++v) atomicAdd(&csh[tx + 16*v], cpart[v]);
    __syncthreads();
    if (t < 64) {
        atomicAdd(&rowsum[b * NFULL + i0 + t], rsh[t]);
        atomicAdd(&colsum[b * NFULL + j0 + t], csh[t]);
    }
}

// ---------------------------------------------------------------------------
// C = 1 - S/(rowsum_i + colsum_j - S) on the 512x512 block (in place),
// plus optional transposed copy CT (for coalesced column-softmins).
__global__ __launch_bounds__(256) void cost_kernel(
    float* __restrict__ C, float* __restrict__ CT,
    const float* __restrict__ rowsum, const float* __restrict__ colsum)
{
    const int b  = blockIdx.z;
    const int i0 = blockIdx.y * 64, j0 = blockIdx.x * 64;
    __shared__ float tile[64][65];
    const int t = threadIdx.x;
    const int lj = t & 63, r4 = t >> 6;
    #pragma unroll
    for (int rr = 0; rr < 64; rr += 4) {
        const int li = rr + r4;
        const size_t idx = ((size_t)b * NREAL + i0 + li) * NREAL + j0 + lj;
        const float s  = C[idx];
        const float rs = rowsum[b * NFULL + i0 + li];
        const float cs = colsum[b * NFULL + j0 + lj];
        const float c = 1.0f - s / (rs + cs - s);
        C[idx] = c;
        tile[li][lj] = c;
    }
    if (CT == nullptr) return;
    __syncthreads();
    #pragma unroll
    for (int rr = 0; rr < 64; rr += 4) {
        const int lc = rr + r4;
        CT[((size_t)b * NREAL + j0 + lc) * NREAL + i0 + lj] = tile[lj][lc];
    }
}

// ---------------------------------------------------------------------------
// hinge = sum relu(0.1 - x3 @ x4^T)   (raw, unnormalized inputs)
__global__ __launch_bounds__(256) void hinge_kernel(
    const float* __restrict__ x3, const float* __restrict__ x4, float* __restrict__ out)
{
    const int b  = blockIdx.z;
    const int i0 = blockIdx.y * 64;
    const int j0 = blockIdx.x * 64;
    __shared__ float As[64][68];
    __shared__ float Bs[64][68];
    const int t = threadIdx.x;
    const int tx = t & 15, ty = t >> 4;
    float acc[4][4] = {};
    const int lk = t & 63, r4 = t >> 6;

    for (int kc = 0; kc < DIM; kc += 64) {
        __syncthreads();
        #pragma unroll
        for (int rr = 0; rr < 64; rr += 4) {
            const int r = rr + r4;
            As[r][lk] = x3[((size_t)b * NPAD + i0 + r) * DIM + kc + lk];
            Bs[r][lk] = x4[((size_t)b * NPAD + j0 + r) * DIM + kc + lk];
        }
        __syncthreads();
        #pragma unroll
        for (int k = 0; k < 64; k += 4) {
            float4 av[4], bv[4];
            #pragma unroll
            for (int u = 0; u < 4; ++u) av[u] = *(const float4*)&As[ty + 16*u][k];
            #pragma unroll
            for (int u = 0; u < 4; ++u) bv[u] = *(const float4*)&Bs[tx + 16*u][k];
            #pragma unroll
            for (int u = 0; u < 4; ++u)
                #pragma unroll
                for (int v = 0; v < 4; ++v) {
                    acc[u][v] += av[u].x * bv[v].x;
                    acc[u][v] += av[u].y * bv[v].y;
                    acc[u][v] += av[u].z * bv[v].z;
                    acc[u][v] += av[u].w * bv[v].w;
                }
        }
    }
    float part = 0.f;
    #pragma unroll
    for (int u = 0; u < 4; ++u)
        #pragma unroll
        for (int v = 0; v < 4; ++v) part += fmaxf(0.1f - acc[u][v], 0.f);
    __shared__ float red[256];
    red[t] = part;
    __syncthreads();
    for (int s = 128; s > 0; s >>= 1) { if (t < s) red[t] += red[t + s]; __syncthreads(); }
    if (t == 0) atomicAdd(out, red[0]);
}

// ---------------------------------------------------------------------------
// Fused softmin pair over the 512x512 real block.
// side 0: ft_i = -eps*LSE_j( h_j - C[i][j]/eps ),  h = (mode? g_in/eps : 0)
// side 1: gt_j over C columns (via CT rows if available, else strided).
// mode 0: write state directly. mode 1: state_out = 0.5*(state_in + new).
// mode 2: atomicAdd( out, sum(new)/BATCH ).
__global__ __launch_bounds__(256) void softmin_kernel(
    const float* __restrict__ C, const float* __restrict__ CT,
    const float* __restrict__ f_in, const float* __restrict__ g_in,
    float* __restrict__ f_out, float* __restrict__ g_out,
    float eps, int mode, float* __restrict__ out)
{
    const int w = threadIdx.x >> 6, lane = threadIdx.x & 63;
    const int gw = blockIdx.x * 4 + w;                 // 0 .. 2*B*512-1
    const int side = (gw >= BATCH * NREAL) ? 1 : 0;
    const int rem  = side ? gw - BATCH * NREAL : gw;
    const int b = rem >> 9, i = rem & (NREAL - 1);
    const float* M;
    size_t stride;
    if (side == 0) { M = C + ((size_t)(b * NREAL + i)) * NREAL; stride = 1; }
    else if (CT)   { M = CT + ((size_t)(b * NREAL + i)) * NREAL; stride = 1; }
    else           { M = C + (size_t)b * NREAL * NREAL + i; stride = NREAL; }
    const float* h_src = (side ? f_in : g_in) + b * NREAL;
    const float inv_eps = 1.0f / eps;

    float m = -3.0e38f, s = 0.f;
    #pragma unroll
    for (int jo = 0; jo < NREAL; jo += 64) {
        const int j = jo + lane;
        const float h = (mode == 0) ? 0.f : h_src[j] * inv_eps;
        const float v = h - M[(size_t)j * stride] * inv_eps;
        if (v > m) { s = s * __expf(m - v) + 1.f; m = v; }
        else        s += __expf(v - m);
    }
    #pragma unroll
    for (int off = 1; off < 64; off <<= 1) {
        const float mo = __shfl_xor(m, off), so = __shfl_xor(s, off);
        const float mn = fmaxf(m, mo);
        s = s * __expf(m - mn) + so * __expf(mo - mn);
        m = mn;
    }
    const float res = -eps * (m + logf(s));

    if (mode == 2) {
        __shared__ float acc4[4];
        if (lane == 0) acc4[w] = res;
        __syncthreads();
        if (threadIdx.x == 0)
            atomicAdd(out, (acc4[0] + acc4[1] + acc4[2] + acc4[3]) * (1.0f / BATCH));
    } else if (lane == 0) {
        float* st = (side ? g_out : f_out) + b * NREAL + i;
        if (mode == 0) *st = res;
        else {
            const float* si = (side ? g_in : f_in) + b * NREAL + i;
            *st = 0.5f * (*si + res);
        }
    }
}

// ---------------------------------------------------------------------------
extern "C" void kernel_launch(void* const* d_in, const int* in_sizes, int n_in,
                              void* d_out, int out_size, void* d_ws, size_t ws_size,
                              hipStream_t stream)
{
    const float* x1 = (const float*)d_in[0];
    const float* x2 = (const float*)d_in[1];
    const float* x3 = (const float*)d_in[2];
    const float* x4 = (const float*)d_in[3];
    float* out = (float*)d_out;

    float* ws = (float*)d_ws;
    const size_t CSZ = (size_t)BATCH * NREAL * NREAL;      // 4,194,304 floats
    const size_t SMALLS = 4 * BATCH * NFULL + 8 * BATCH * NREAL;
    const bool use_ct = ws_size >= (2 * CSZ + SMALLS) * sizeof(float);

    float* C      = ws;
    float* CT     = use_ct ? C + CSZ : nullptr;
    float* tail   = use_ct ? CT + CSZ : C + CSZ;
    float* rowsum = tail;
    float* colsum = rowsum + BATCH * NFULL;
    float* invn1  = colsum + BATCH * NFULL;
    float* invn2  = invn1 + BATCH * NFULL;
    float* fs     = invn2 + BATCH * NFULL;                 // [2][B*NREAL]
    float* gs     = fs + 2 * BATCH * NREAL;                // [2][B*NREAL]
    const int PS  = BATCH * NREAL;                         // 8192

    hipMemsetAsync(out, 0, 2 * sizeof(float), stream);
    hipMemsetAsync(rowsum, 0, 2 * BATCH * NFULL * sizeof(float), stream);

    norm_kernel<<<(2 * BATCH * NFULL) / 4, 256, 0, stream>>>(x1, x3, x2, x4, invn1, invn2);
    gram_kernel<<<dim3(14, 14, BATCH), 256, 0, stream>>>(x1, x3, x2, x4, invn1, invn2,
                                                         C, rowsum, colsum);
    cost_kernel<<<dim3(8, 8, BATCH), 256, 0, stream>>>(C, CT, rowsum, colsum);
    hinge_kernel<<<dim3(6, 6, BATCH), 256, 0, stream>>>(x3, x4, out);

    const int SMB = (2 * BATCH * NREAL) / 4;               // 4096 blocks
    const float epsl[8] = {9.0f, 9.0f, 2.25f, 0.5625f, 0.140625f,
                           0.03515625f, 0.0087890625f, 0.0025f};

    // init: f0 = softmin(9, C, b_log); g0 = softmin(9, C^T, a_log)
    softmin_kernel<<<SMB, 256, 0, stream>>>(C, CT, fs, gs, fs, gs, 9.0f, 0, out);
    int cur = 0;
    for (int k = 0; k < 8; ++k) {
        softmin_kernel<<<SMB, 256, 0, stream>>>(C, CT,
            fs + cur * PS, gs + cur * PS,
            fs + (1 - cur) * PS, gs + (1 - cur) * PS,
            epsl[k], 1, out);
        cur ^= 1;
    }
    // final extrapolation at eps = blur^2, accumulate scon into out[1]
    softmin_kernel<<<SMB, 256, 0, stream>>>(C, CT,
        fs + cur * PS, gs + cur * PS, nullptr, nullptr,
        0.0025f, 2, out + 1);
}

// Round 3
// 290.738 us; speedup vs baseline: 1.6615x; 1.6615x over previous
//
#include <hip/hip_runtime.h>
#include <cstddef>
#include <cstdint>

#define BATCH 16
#define NFULL 896   // 512 real + 384 pad
#define NREAL 512
#define NPAD  384
#define DIM   256

typedef short bf16x8 __attribute__((ext_vector_type(8)));
typedef float f32x4  __attribute__((ext_vector_type(4)));
typedef int   int4v  __attribute__((ext_vector_type(4)));

// round-to-nearest-even f32 -> bf16 bits (no NaN inputs here)
static __device__ inline short f2bf(float v) {
    unsigned u = __float_as_uint(v);
    unsigned r = (u + 0x7FFFu + ((u >> 16) & 1u)) >> 16;
    return (short)r;
}
static __device__ inline float bf2f(short s) {
    return __uint_as_float(((unsigned)(unsigned short)s) << 16);
}

// ---------------------------------------------------------------------------
// Per-row: norm, inv-norm, and split-bf16 (hi|lo) planes of the normalized row.
// One block per (side, b, row); 256 threads = 1 per k element.
__global__ __launch_bounds__(256) void norm_cvt_kernel(
    const float* __restrict__ x1, const float* __restrict__ x3,
    const float* __restrict__ x2, const float* __restrict__ x4,
    short* __restrict__ A1s, short* __restrict__ B2s,
    float* __restrict__ invn1, float* __restrict__ invn2,
    float* __restrict__ n1, float* __restrict__ n2)
{
    const int gid  = blockIdx.x;                 // 0 .. 2*B*NFULL-1
    const int side = gid >= BATCH * NFULL;
    const int rem  = gid - (side ? BATCH * NFULL : 0);
    const int b = rem / NFULL, row = rem % NFULL;
    const int t = threadIdx.x;
    const float* src;
    if (!side) src = (row < NREAL) ? x1 + ((size_t)b * NREAL + row) * DIM
                                   : x3 + ((size_t)b * NPAD + (row - NREAL)) * DIM;
    else       src = (row < NREAL) ? x2 + ((size_t)b * NREAL + row) * DIM
                                   : x4 + ((size_t)b * NPAD + (row - NREAL)) * DIM;
    const float x = src[t];
    float ss = x * x;
    #pragma unroll
    for (int m = 1; m < 64; m <<= 1) ss += __shfl_xor(ss, m);
    __shared__ float wsum[4];
    if ((t & 63) == 0) wsum[t >> 6] = ss;
    __syncthreads();
    ss = wsum[0] + wsum[1] + wsum[2] + wsum[3];
    const float nrm = sqrtf(ss);
    const float inv = 1.0f / fmaxf(nrm, 1e-12f);
    if (t == 0) {
        (side ? invn2 : invn1)[b * NFULL + row] = inv;
        (side ? n2 : n1)[b * NFULL + row] = nrm;
    }
    const float val = x * inv;
    const short hi = f2bf(val);
    const short lo = f2bf(val - bf2f(hi));
    short* dst = (side ? B2s : A1s) + ((size_t)b * NFULL + row) * 512;
    dst[t] = hi;
    dst[256 + t] = lo;
}

// ---------------------------------------------------------------------------
// MFMA gram: S = exp(10 * f1n @ f2n^T) over 896x896 via split-bf16 K=768
// (hi*hi + lo*hi + hi*lo). Epilogue: row/col sums (global atomics after shfl
// reduce), S store on real 512x512 block, hinge on pad x pad block.
__global__ __launch_bounds__(256) void gram_mfma_kernel(
    const short* __restrict__ A1s, const short* __restrict__ B2s,
    const float* __restrict__ n1, const float* __restrict__ n2,
    float* __restrict__ S, float* __restrict__ rowsum, float* __restrict__ colsum,
    float* __restrict__ out_hinge)
{
    const int b  = blockIdx.z;
    const int i0 = blockIdx.y * 128;
    const int j0 = blockIdx.x * 128;
    __shared__ __align__(16) short As[128][72];   // 144B rows: b128-aligned, bank-uniform
    __shared__ __align__(16) short Bs[128][72];
    const int t = threadIdx.x;
    const int wid = t >> 6, lane = t & 63;
    const int wr = wid >> 1, wc = wid & 1;        // 2x2 waves, 64x64 each
    const int lr = lane & 15, lg = lane >> 4;
    f32x4 acc[4][4] = {};

    const short* gA = A1s + ((size_t)b * NFULL + i0) * 512;
    const short* gB = B2s + ((size_t)b * NFULL + j0) * 512;

    for (int step = 0; step < 12; ++step) {       // K' = 768, BK = 64
        const int kb   = step * 64;
        const int koff = kb & 255;
        const int aoff = (((kb >> 8) == 1) ? 256 : 0) + koff;  // pass1 uses A-lo
        const int boff = (((kb >> 8) == 2) ? 256 : 0) + koff;  // pass2 uses B-lo
        __syncthreads();
        #pragma unroll
        for (int p = 0; p < 4; ++p) {
            const int s = p * 256 + t;            // 1024 16B slots per tile
            const int row = s >> 3, c = s & 7;
            *(int4v*)((char*)&As[0][0] + row * 144 + c * 16) =
                *(const int4v*)(gA + (size_t)row * 512 + aoff + c * 8);
            *(int4v*)((char*)&Bs[0][0] + row * 144 + c * 16) =
                *(const int4v*)(gB + (size_t)row * 512 + boff + c * 8);
        }
        __syncthreads();
        #pragma unroll
        for (int kk = 0; kk < 64; kk += 32) {
            bf16x8 af[4], bg[4];
            #pragma unroll
            for (int m = 0; m < 4; ++m)
                af[m] = *(const bf16x8*)((const char*)&As[0][0]
                         + (wr * 64 + m * 16 + lr) * 144 + kk * 2 + lg * 16);
            #pragma unroll
            for (int n = 0; n < 4; ++n)
                bg[n] = *(const bf16x8*)((const char*)&Bs[0][0]
                         + (wc * 64 + n * 16 + lr) * 144 + kk * 2 + lg * 16);
            #pragma unroll
            for (int m = 0; m < 4; ++m)
                #pragma unroll
                for (int n = 0; n < 4; ++n)
                    acc[m][n] = __builtin_amdgcn_mfma_f32_16x16x32_bf16(
                        af[m], bg[n], acc[m][n], 0, 0, 0);
        }
    }

    const bool storeS = (blockIdx.y < 4) && (blockIdx.x < 4);
    const bool hingeB = (blockIdx.y >= 4) && (blockIdx.x >= 4);
    float rp[4][4] = {};
    float cp[4] = {};
    float hp = 0.f;
    #pragma unroll
    for (int m = 0; m < 4; ++m) {
        const int row0 = i0 + wr * 64 + m * 16 + lg * 4;
        float n1v[4] = {0.f, 0.f, 0.f, 0.f};
        if (hingeB) {
            #pragma unroll
            for (int r = 0; r < 4; ++r) n1v[r] = n1[b * NFULL + row0 + r];
        }
        #pragma unroll
        for (int n = 0; n < 4; ++n) {
            const int col = j0 + wc * 64 + n * 16 + lr;
            const f32x4 f = acc[m][n];
            float cn = 0.f;
            float sv[4];
            #pragma unroll
            for (int r = 0; r < 4; ++r) {
                sv[r] = __expf(10.f * f[r]);
                rp[m][r] += sv[r];
                cn += sv[r];
            }
            cp[n] += cn;
            if (storeS) {
                #pragma unroll
                for (int r = 0; r < 4; ++r)
                    S[((size_t)b * NREAL + row0 + r) * NREAL + col] = sv[r];
            }
            if (hingeB) {
                const float nn2 = n2[b * NFULL + col];
                #pragma unroll
                for (int r = 0; r < 4; ++r)
                    hp += fmaxf(0.1f - f[r] * n1v[r] * nn2, 0.f);
            }
        }
    }
    // rowsum: reduce 16 cols (lr bits), 4 lanes (lg) write distinct rows
    #pragma unroll
    for (int m = 0; m < 4; ++m)
        #pragma unroll
        for (int r = 0; r < 4; ++r) {
            float v = rp[m][r];
            v += __shfl_xor(v, 1); v += __shfl_xor(v, 2);
            v += __shfl_xor(v, 4); v += __shfl_xor(v, 8);
            if (lr == 0)
                atomicAdd(&rowsum[b * NFULL + i0 + wr * 64 + m * 16 + lg * 4 + r], v);
        }
    // colsum: reduce 4 row-groups (lg bits), 16 lanes write distinct cols
    #pragma unroll
    for (int n = 0; n < 4; ++n) {
        float v = cp[n];
        v += __shfl_xor(v, 16); v += __shfl_xor(v, 32);
        if (lg == 0)
            atomicAdd(&colsum[b * NFULL + j0 + wc * 64 + n * 16 + lr], v);
    }
    if (hingeB) {
        #pragma unroll
        for (int m = 1; m < 64; m <<= 1) hp += __shfl_xor(hp, m);
        if (lane == 0) atomicAdd(out_hinge, hp);
    }
}

// ---------------------------------------------------------------------------
// Fallback fp32 kernels (used only if ws_size is too small for the MFMA path).
__global__ __launch_bounds__(256) void norm_kernel(
    const float* __restrict__ x1, const float* __restrict__ x3,
    const float* __restrict__ x2, const float* __restrict__ x4,
    float* __restrict__ invn1, float* __restrict__ invn2)
{
    const int w = threadIdx.x >> 6, lane = threadIdx.x & 63;
    const int rg = blockIdx.x * 4 + w;
    const int side = rg / (BATCH * NFULL);
    const int rem  = rg - side * (BATCH * NFULL);
    const int b = rem / NFULL, r = rem % NFULL;
    const float* src;
    if (side == 0)
        src = (r < NREAL) ? x1 + ((size_t)b * NREAL + r) * DIM
                          : x3 + ((size_t)b * NPAD + (r - NREAL)) * DIM;
    else
        src = (r < NREAL) ? x2 + ((size_t)b * NREAL + r) * DIM
                          : x4 + ((size_t)b * NPAD + (r - NREAL)) * DIM;
    float4 v = ((const float4*)src)[lane];
    float ss = v.x*v.x + v.y*v.y + v.z*v.z + v.w*v.w;
    #pragma unroll
    for (int m = 1; m < 64; m <<= 1) ss += __shfl_xor(ss, m);
    if (lane == 0)
        (side == 0 ? invn1 : invn2)[b * NFULL + r] = 1.0f / fmaxf(sqrtf(ss), 1e-12f);
}

__global__ __launch_bounds__(256) void gram_kernel(
    const float* __restrict__ x1, const float* __restrict__ x3,
    const float* __restrict__ x2, const float* __restrict__ x4,
    const float* __restrict__ invn1, const float* __restrict__ invn2,
    float* __restrict__ S, float* __restrict__ rowsum, float* __restrict__ colsum)
{
    const int b  = blockIdx.z;
    const int i0 = blockIdx.y * 64;
    const int j0 = blockIdx.x * 64;
    __shared__ float As[64][68];
    __shared__ float Bs[64][68];
    __shared__ float rsh[64], csh[64];
    const int t = threadIdx.x;
    const int tx = t & 15, ty = t >> 4;
    if (t < 64) { rsh[t] = 0.f; csh[t] = 0.f; }
    float acc[4][4] = {};
    const int lk = t & 63, r4 = t >> 6;
    for (int kc = 0; kc < DIM; kc += 64) {
        __syncthreads();
        #pragma unroll
        for (int rr = 0; rr < 64; rr += 4) {
            const int r = rr + r4;
            const int gi = i0 + r;
            const float* pa = (gi < NREAL) ? x1 + ((size_t)b * NREAL + gi) * DIM
                                           : x3 + ((size_t)b * NPAD + (gi - NREAL)) * DIM;
            As[r][lk] = pa[kc + lk] * invn1[b * NFULL + gi];
            const int gj = j0 + r;
            const float* pb = (gj < NREAL) ? x2 + ((size_t)b * NREAL + gj) * DIM
                                           : x4 + ((size_t)b * NPAD + (gj - NREAL)) * DIM;
            Bs[r][lk] = pb[kc + lk] * invn2[b * NFULL + gj];
        }
        __syncthreads();
        #pragma unroll
        for (int k = 0; k < 64; k += 4) {
            float4 av[4], bv[4];
            #pragma unroll
            for (int u = 0; u < 4; ++u) av[u] = *(const float4*)&As[ty + 16*u][k];
            #pragma unroll
            for (int u = 0; u < 4; ++u) bv[u] = *(const float4*)&Bs[tx + 16*u][k];
            #pragma unroll
            for (int u = 0; u < 4; ++u)
                #pragma unroll
                for (int v = 0; v < 4; ++v) {
                    acc[u][v] += av[u].x * bv[v].x;
                    acc[u][v] += av[u].y * bv[v].y;
                    acc[u][v] += av[u].z * bv[v].z;
                    acc[u][v] += av[u].w * bv[v].w;
                }
        }
    }
    float rpart[4] = {}, cpart[4] = {};
    const bool store = (i0 < NREAL) && (j0 < NREAL);
    #pragma unroll
    for (int u = 0; u < 4; ++u)
        #pragma unroll
        for (int v = 0; v < 4; ++v) {
            const float s = __expf(10.0f * acc[u][v]);
            rpart[u] += s;
            cpart[v] += s;
            if (store) {
                const int i = i0 + ty + 16*u, j = j0 + tx + 16*v;
                S[((size_t)b * NREAL + i) * NREAL + j] = s;
            }
        }
    #pragma unroll
    for (int u = 0; u < 4; ++u) atomicAdd(&rsh[ty + 16*u], rpart[u]);
    #pragma unroll
    for (int v = 0; v < 4; ++v) atomicAdd(&csh[tx + 16*v], cpart[v]);
    __syncthreads();
    if (t < 64) {
        atomicAdd(&rowsum[b * NFULL + i0 + t], rsh[t]);
        atomicAdd(&colsum[b * NFULL + j0 + t], csh[t]);
    }
}

__global__ __launch_bounds__(256) void hinge_kernel(
    const float* __restrict__ x3, const float* __restrict__ x4, float* __restrict__ out)
{
    const int b  = blockIdx.z;
    const int i0 = blockIdx.y * 64;
    const int j0 = blockIdx.x * 64;
    __shared__ float As[64][68];
    __shared__ float Bs[64][68];
    const int t = threadIdx.x;
    const int tx = t & 15, ty = t >> 4;
    float acc[4][4] = {};
    const int lk = t & 63, r4 = t >> 6;
    for (int kc = 0; kc < DIM; kc += 64) {
        __syncthreads();
        #pragma unroll
        for (int rr = 0; rr < 64; rr += 4) {
            const int r = rr + r4;
            As[r][lk] = x3[((size_t)b * NPAD + i0 + r) * DIM + kc + lk];
            Bs[r][lk] = x4[((size_t)b * NPAD + j0 + r) * DIM + kc + lk];
        }
        __syncthreads();
        #pragma unroll
        for (int k = 0; k < 64; k += 4) {
            float4 av[4], bv[4];
            #pragma unroll
            for (int u = 0; u < 4; ++u) av[u] = *(const float4*)&As[ty + 16*u][k];
            #pragma unroll
            for (int u = 0; u < 4; ++u) bv[u] = *(const float4*)&Bs[tx + 16*u][k];
            #pragma unroll
            for (int u = 0; u < 4; ++u)
                #pragma unroll
                for (int v = 0; v < 4; ++v) {
                    acc[u][v] += av[u].x * bv[v].x;
                    acc[u][v] += av[u].y * bv[v].y;
                    acc[u][v] += av[u].z * bv[v].z;
                    acc[u][v] += av[u].w * bv[v].w;
                }
        }
    }
    float part = 0.f;
    #pragma unroll
    for (int u = 0; u < 4; ++u)
        #pragma unroll
        for (int v = 0; v < 4; ++v) part += fmaxf(0.1f - acc[u][v], 0.f);
    __shared__ float red[256];
    red[t] = part;
    __syncthreads();
    for (int s = 128; s > 0; s >>= 1) { if (t < s) red[t] += red[t + s]; __syncthreads(); }
    if (t == 0) atomicAdd(out, red[0]);
}

// ---------------------------------------------------------------------------
// C = 1 - S/(rowsum_i + colsum_j - S) in place, plus optional transposed copy.
__global__ __launch_bounds__(256) void cost_kernel(
    float* __restrict__ C, float* __restrict__ CT,
    const float* __restrict__ rowsum, const float* __restrict__ colsum)
{
    const int b  = blockIdx.z;
    const int i0 = blockIdx.y * 64, j0 = blockIdx.x * 64;
    __shared__ float tile[64][65];
    const int t = threadIdx.x;
    const int lj = t & 63, r4 = t >> 6;
    #pragma unroll
    for (int rr = 0; rr < 64; rr += 4) {
        const int li = rr + r4;
        const size_t idx = ((size_t)b * NREAL + i0 + li) * NREAL + j0 + lj;
        const float s  = C[idx];
        const float rs = rowsum[b * NFULL + i0 + li];
        const float cs = colsum[b * NFULL + j0 + lj];
        const float c = 1.0f - s / (rs + cs - s);
        C[idx] = c;
        tile[li][lj] = c;
    }
    if (CT == nullptr) return;
    __syncthreads();
    #pragma unroll
    for (int rr = 0; rr < 64; rr += 4) {
        const int lc = rr + r4;
        CT[((size_t)b * NREAL + j0 + lc) * NREAL + i0 + lj] = tile[lj][lc];
    }
}

// ---------------------------------------------------------------------------
// Branchless two-pass softmin; one wave handles 4 rows of one (side, b).
// side 0: f-rows over C; side 1: g-rows over CT (or strided C fallback).
// mode 0: write state. mode 1: 0.5*(old + new). mode 2: atomicAdd(out, sum/B).
__global__ __launch_bounds__(256) void softmin_kernel(
    const float* __restrict__ C, const float* __restrict__ CT,
    const float* __restrict__ f_in, const float* __restrict__ g_in,
    float* __restrict__ f_out, float* __restrict__ g_out,
    float eps, int mode, float* __restrict__ out)
{
    const int w = threadIdx.x >> 6, lane = threadIdx.x & 63;
    const int rg = blockIdx.x * 4 + w;           // 0 .. 4095
    const int side = rg >= 2 * BATCH * (NREAL / 8) ? 1 : 0;  // 2048 groups/side
    const int rem  = side ? rg - 2048 : rg;
    const int b  = rem >> 7;
    const int ib = (rem & 127) * 4;
    const float inv_eps = 1.0f / eps;
    const float* h_src = (side ? f_in : g_in) + b * NREAL;

    float hv[8];
    #pragma unroll
    for (int q = 0; q < 8; ++q)
        hv[q] = (mode == 0) ? 0.f : h_src[q * 64 + lane] * inv_eps;

    const float* Mb;
    size_t stride;
    if (!side)   { Mb = C  + ((size_t)(b * NREAL + ib)) * NREAL; stride = 1; }
    else if (CT) { Mb = CT + ((size_t)(b * NREAL + ib)) * NREAL; stride = 1; }
    else         { Mb = C + (size_t)b * NREAL * NREAL + ib;      stride = NREAL; }

    float res[4];
    float acc_res = 0.f;
    #pragma unroll
    for (int rr = 0; rr < 4; ++rr) {
        const float* M = (stride == 1) ? (Mb + (size_t)rr * NREAL) : (Mb + rr);
        float v[8];
        #pragma unroll
        for (int q = 0; q < 8; ++q)
            v[q] = hv[q] - M[(size_t)(q * 64 + lane) * stride] * inv_eps;
        float mx = v[0];
        #pragma unroll
        for (int q = 1; q < 8; ++q) mx = fmaxf(mx, v[q]);
        #pragma unroll
        for (int off = 1; off < 64; off <<= 1) mx = fmaxf(mx, __shfl_xor(mx, off));
        float s = 0.f;
        #pragma unroll
        for (int q = 0; q < 8; ++q) s += __expf(v[q] - mx);
        #pragma unroll
        for (int off = 1; off < 64; off <<= 1) s += __shfl_xor(s, off);
        res[rr] = -eps * (mx + logf(s));
        acc_res += res[rr];
    }

    if (mode == 2) {
        if (lane == 0) atomicAdd(out, acc_res * (1.0f / BATCH));
    } else if (lane == 0) {
        float* st = (side ? g_out : f_out) + b * NREAL + ib;
        if (mode == 0) {
            st[0] = res[0]; st[1] = res[1]; st[2] = res[2]; st[3] = res[3];
        } else {
            const float* si = (side ? g_in : f_in) + b * NREAL + ib;
            st[0] = 0.5f * (si[0] + res[0]);
            st[1] = 0.5f * (si[1] + res[1]);
            st[2] = 0.5f * (si[2] + res[2]);
            st[3] = 0.5f * (si[3] + res[3]);
        }
    }
}

// ---------------------------------------------------------------------------
extern "C" void kernel_launch(void* const* d_in, const int* in_sizes, int n_in,
                              void* d_out, int out_size, void* d_ws, size_t ws_size,
                              hipStream_t stream)
{
    const float* x1 = (const float*)d_in[0];
    const float* x2 = (const float*)d_in[1];
    const float* x3 = (const float*)d_in[2];
    const float* x4 = (const float*)d_in[3];
    float* out = (float*)d_out;

    char* p = (char*)d_ws;
    const size_t CBYTES = (size_t)BATCH * NREAL * NREAL * 4;  // 16.78 MB
    const size_t ABYTES = (size_t)BATCH * NFULL * 512 * 2;    // 14.68 MB
    const size_t NB = (size_t)BATCH * NFULL * 4;              // 57 KB
    const size_t PB = (size_t)BATCH * NREAL * 4;              // 32 KB
    const size_t SMALLB = 6 * NB + 4 * PB;
    const bool mfma_ok = ws_size >= CBYTES + 2 * ABYTES + SMALLB;

    float* C = (float*)p; p += CBYTES;
    short* A1s = nullptr; short* B2s = nullptr;
    if (mfma_ok) { A1s = (short*)p; p += ABYTES; B2s = (short*)p; p += ABYTES; }
    float* rowsum = (float*)p; p += NB;
    float* colsum = (float*)p; p += NB;
    float* invn1  = (float*)p; p += NB;
    float* invn2  = (float*)p; p += NB;
    float* n1     = (float*)p; p += NB;
    float* n2     = (float*)p; p += NB;
    float* fs     = (float*)p; p += 2 * PB;
    float* gs     = (float*)p; p += 2 * PB;
    float* CT = nullptr;
    if (ws_size >= (size_t)(p - (char*)d_ws) + CBYTES) { CT = (float*)p; p += CBYTES; }
    const int PS = BATCH * NREAL;

    hipMemsetAsync(out, 0, 2 * sizeof(float), stream);
    hipMemsetAsync(rowsum, 0, 2 * NB, stream);

    if (mfma_ok) {
        norm_cvt_kernel<<<2 * BATCH * NFULL, 256, 0, stream>>>(
            x1, x3, x2, x4, A1s, B2s, invn1, invn2, n1, n2);
        gram_mfma_kernel<<<dim3(7, 7, BATCH), 256, 0, stream>>>(
            A1s, B2s, n1, n2, C, rowsum, colsum, out);
    } else {
        norm_kernel<<<(2 * BATCH * NFULL) / 4, 256, 0, stream>>>(
            x1, x3, x2, x4, invn1, invn2);
        gram_kernel<<<dim3(14, 14, BATCH), 256, 0, stream>>>(
            x1, x3, x2, x4, invn1, invn2, C, rowsum, colsum);
        hinge_kernel<<<dim3(6, 6, BATCH), 256, 0, stream>>>(x3, x4, out);
    }
    cost_kernel<<<dim3(8, 8, BATCH), 256, 0, stream>>>(C, CT, rowsum, colsum);

    const int SMB = 1024;   // 4096 row-groups / 4 waves per block
    const float epsl[8] = {9.0f, 9.0f, 2.25f, 0.5625f, 0.140625f,
                           0.03515625f, 0.0087890625f, 0.0025f};

    softmin_kernel<<<SMB, 256, 0, stream>>>(C, CT, fs, gs, fs, gs, 9.0f, 0, out);
    int cur = 0;
    for (int k = 0; k < 8; ++k) {
        softmin_kernel<<<SMB, 256, 0, stream>>>(C, CT,
            fs + cur * PS, gs + cur * PS,
            fs + (1 - cur) * PS, gs + (1 - cur) * PS,
            epsl[k], 1, out);
        cur ^= 1;
    }
    softmin_kernel<<<SMB, 256, 0, stream>>>(C, CT,
        fs + cur * PS, gs + cur * PS, nullptr, nullptr,
        0.0025f, 2, out + 1);
}

// Round 4
// 200.792 us; speedup vs baseline: 2.4057x; 1.4480x over previous
//
#include <hip/hip_runtime.h>
#include <cstddef>
#include <cstdint>

#define BATCH 16
#define NFULL 896   // 512 real + 384 pad
#define NREAL 512
#define NPAD  384
#define DIM   256

typedef short bf16x8 __attribute__((ext_vector_type(8)));
typedef short s16x4  __attribute__((ext_vector_type(4)));
typedef float f32x4  __attribute__((ext_vector_type(4)));
typedef int   int4v  __attribute__((ext_vector_type(4)));

// round-to-nearest-even f32 -> bf16 bits (no NaN inputs here)
static __device__ inline short f2bf(float v) {
    unsigned u = __float_as_uint(v);
    unsigned r = (u + 0x7FFFu + ((u >> 16) & 1u)) >> 16;
    return (short)r;
}
static __device__ inline float bf2f(short s) {
    return __uint_as_float(((unsigned)(unsigned short)s) << 16);
}

// ---------------------------------------------------------------------------
// One wave per row: norm, inv-norm, split-bf16 (hi|lo) planes of normalized row.
// Also zero-inits rowsum/colsum and out[0..1] (replaces two memset nodes).
__global__ __launch_bounds__(256) void norm_cvt_kernel(
    const float* __restrict__ x1, const float* __restrict__ x3,
    const float* __restrict__ x2, const float* __restrict__ x4,
    short* __restrict__ A1s, short* __restrict__ B2s,
    float* __restrict__ invn1, float* __restrict__ invn2,
    float* __restrict__ n1, float* __restrict__ n2,
    float* __restrict__ zero_base, float* __restrict__ out)
{
    const int t = threadIdx.x;
    const int gid = blockIdx.x * 256 + t;
    if (gid < 2 * BATCH * NFULL) zero_base[gid] = 0.f;   // rowsum+colsum contiguous
    if (gid < 2) out[gid] = 0.f;

    const int w = t >> 6, lane = t & 63;
    const int rg = blockIdx.x * 4 + w;           // 0 .. 2*B*NFULL-1
    const int side = rg >= BATCH * NFULL;
    const int rem  = rg - (side ? BATCH * NFULL : 0);
    const int b = rem / NFULL, row = rem % NFULL;
    const float* src;
    if (!side) src = (row < NREAL) ? x1 + ((size_t)b * NREAL + row) * DIM
                                   : x3 + ((size_t)b * NPAD + (row - NREAL)) * DIM;
    else       src = (row < NREAL) ? x2 + ((size_t)b * NREAL + row) * DIM
                                   : x4 + ((size_t)b * NPAD + (row - NREAL)) * DIM;
    const f32x4 v = ((const f32x4*)src)[lane];
    float ss = v[0]*v[0] + v[1]*v[1] + v[2]*v[2] + v[3]*v[3];
    #pragma unroll
    for (int m = 1; m < 64; m <<= 1) ss += __shfl_xor(ss, m);   // all lanes get total
    const float nrm = sqrtf(ss);
    const float inv = 1.0f / fmaxf(nrm, 1e-12f);
    if (lane == 0) {
        (side ? invn2 : invn1)[b * NFULL + row] = inv;
        (side ? n2 : n1)[b * NFULL + row] = nrm;
    }
    s16x4 hi, lo;
    #pragma unroll
    for (int c = 0; c < 4; ++c) {
        const float val = v[c] * inv;
        hi[c] = f2bf(val);
        lo[c] = f2bf(val - bf2f(hi[c]));
    }
    short* dst = (side ? B2s : A1s) + ((size_t)b * NFULL + row) * 512;
    *(s16x4*)(dst + lane * 4) = hi;
    *(s16x4*)(dst + 256 + lane * 4) = lo;
}

// ---------------------------------------------------------------------------
// MFMA gram: S = exp(10 * f1n @ f2n^T) over 896x896 via split-bf16 K=768
// (hi*hi + lo*hi + hi*lo). XCD-locality swizzle: flat%8 selects XCD (default
// round-robin dispatch), XCD k owns batches {2k,2k+1}; per-XCD operand set
// = 3.7 MB <= 4 MB L2, so A/B planes are fetched from HBM ~once.
__global__ __launch_bounds__(256) void gram_mfma_kernel(
    const short* __restrict__ A1s, const short* __restrict__ B2s,
    const float* __restrict__ n1, const float* __restrict__ n2,
    float* __restrict__ S, float* __restrict__ rowsum, float* __restrict__ colsum,
    float* __restrict__ out_hinge)
{
    const int flat = blockIdx.x;                  // 784 = 8 XCD * 98
    const int id = (flat & 7) * 98 + (flat >> 3);
    const int b  = id / 49;
    const int r49 = id % 49;
    const int by = r49 / 7, bx = r49 % 7;
    const int i0 = by * 128;
    const int j0 = bx * 128;
    __shared__ __align__(16) short As[128][72];   // 144B rows: b128-aligned, 2-way banks
    __shared__ __align__(16) short Bs[128][72];
    const int t = threadIdx.x;
    const int wid = t >> 6, lane = t & 63;
    const int wr = wid >> 1, wc = wid & 1;        // 2x2 waves, 64x64 each
    const int lr = lane & 15, lg = lane >> 4;
    f32x4 acc[4][4] = {};

    const short* gA = A1s + ((size_t)b * NFULL + i0) * 512;
    const short* gB = B2s + ((size_t)b * NFULL + j0) * 512;

    for (int step = 0; step < 12; ++step) {       // K' = 768, BK = 64
        const int kb   = step * 64;
        const int koff = kb & 255;
        const int aoff = (((kb >> 8) == 1) ? 256 : 0) + koff;  // pass1 uses A-lo
        const int boff = (((kb >> 8) == 2) ? 256 : 0) + koff;  // pass2 uses B-lo
        __syncthreads();
        #pragma unroll
        for (int p = 0; p < 4; ++p) {
            const int s = p * 256 + t;            // 1024 16B slots per tile
            const int row = s >> 3, c = s & 7;
            *(int4v*)((char*)&As[0][0] + row * 144 + c * 16) =
                *(const int4v*)(gA + (size_t)row * 512 + aoff + c * 8);
            *(int4v*)((char*)&Bs[0][0] + row * 144 + c * 16) =
                *(const int4v*)(gB + (size_t)row * 512 + boff + c * 8);
        }
        __syncthreads();
        #pragma unroll
        for (int kk = 0; kk < 64; kk += 32) {
            bf16x8 af[4], bg[4];
            #pragma unroll
            for (int m = 0; m < 4; ++m)
                af[m] = *(const bf16x8*)((const char*)&As[0][0]
                         + (wr * 64 + m * 16 + lr) * 144 + kk * 2 + lg * 16);
            #pragma unroll
            for (int n = 0; n < 4; ++n)
                bg[n] = *(const bf16x8*)((const char*)&Bs[0][0]
                         + (wc * 64 + n * 16 + lr) * 144 + kk * 2 + lg * 16);
            #pragma unroll
            for (int m = 0; m < 4; ++m)
                #pragma unroll
                for (int n = 0; n < 4; ++n)
                    acc[m][n] = __builtin_amdgcn_mfma_f32_16x16x32_bf16(
                        af[m], bg[n], acc[m][n], 0, 0, 0);
        }
    }

    const bool storeS = (by < 4) && (bx < 4);
    const bool hingeB = (by >= 4) && (bx >= 4);
    float rp[4][4] = {};
    float cp[4] = {};
    float hp = 0.f;
    #pragma unroll
    for (int m = 0; m < 4; ++m) {
        const int row0 = i0 + wr * 64 + m * 16 + lg * 4;
        float n1v[4] = {0.f, 0.f, 0.f, 0.f};
        if (hingeB) {
            #pragma unroll
            for (int r = 0; r < 4; ++r) n1v[r] = n1[b * NFULL + row0 + r];
        }
        #pragma unroll
        for (int n = 0; n < 4; ++n) {
            const int col = j0 + wc * 64 + n * 16 + lr;
            const f32x4 f = acc[m][n];
            float cn = 0.f;
            float sv[4];
            #pragma unroll
            for (int r = 0; r < 4; ++r) {
                sv[r] = __expf(10.f * f[r]);
                rp[m][r] += sv[r];
                cn += sv[r];
            }
            cp[n] += cn;
            if (storeS) {
                #pragma unroll
                for (int r = 0; r < 4; ++r)
                    S[((size_t)b * NREAL + row0 + r) * NREAL + col] = sv[r];
            }
            if (hingeB) {
                const float nn2 = n2[b * NFULL + col];
                #pragma unroll
                for (int r = 0; r < 4; ++r)
                    hp += fmaxf(0.1f - f[r] * n1v[r] * nn2, 0.f);
            }
        }
    }
    #pragma unroll
    for (int m = 0; m < 4; ++m)
        #pragma unroll
        for (int r = 0; r < 4; ++r) {
            float v = rp[m][r];
            v += __shfl_xor(v, 1); v += __shfl_xor(v, 2);
            v += __shfl_xor(v, 4); v += __shfl_xor(v, 8);
            if (lr == 0)
                atomicAdd(&rowsum[b * NFULL + i0 + wr * 64 + m * 16 + lg * 4 + r], v);
        }
    #pragma unroll
    for (int n = 0; n < 4; ++n) {
        float v = cp[n];
        v += __shfl_xor(v, 16); v += __shfl_xor(v, 32);
        if (lg == 0)
            atomicAdd(&colsum[b * NFULL + j0 + wc * 64 + n * 16 + lr], v);
    }
    if (hingeB) {
        #pragma unroll
        for (int m = 1; m < 64; m <<= 1) hp += __shfl_xor(hp, m);
        if (lane == 0) atomicAdd(out_hinge, hp);
    }
}

// ---------------------------------------------------------------------------
// Fallback fp32 kernels (only if ws_size too small for the MFMA path).
__global__ __launch_bounds__(256) void norm_kernel(
    const float* __restrict__ x1, const float* __restrict__ x3,
    const float* __restrict__ x2, const float* __restrict__ x4,
    float* __restrict__ invn1, float* __restrict__ invn2)
{
    const int w = threadIdx.x >> 6, lane = threadIdx.x & 63;
    const int rg = blockIdx.x * 4 + w;
    const int side = rg / (BATCH * NFULL);
    const int rem  = rg - side * (BATCH * NFULL);
    const int b = rem / NFULL, r = rem % NFULL;
    const float* src;
    if (side == 0)
        src = (r < NREAL) ? x1 + ((size_t)b * NREAL + r) * DIM
                          : x3 + ((size_t)b * NPAD + (r - NREAL)) * DIM;
    else
        src = (r < NREAL) ? x2 + ((size_t)b * NREAL + r) * DIM
                          : x4 + ((size_t)b * NPAD + (r - NREAL)) * DIM;
    float4 v = ((const float4*)src)[lane];
    float ss = v.x*v.x + v.y*v.y + v.z*v.z + v.w*v.w;
    #pragma unroll
    for (int m = 1; m < 64; m <<= 1) ss += __shfl_xor(ss, m);
    if (lane == 0)
        (side == 0 ? invn1 : invn2)[b * NFULL + r] = 1.0f / fmaxf(sqrtf(ss), 1e-12f);
}

__global__ __launch_bounds__(256) void gram_kernel(
    const float* __restrict__ x1, const float* __restrict__ x3,
    const float* __restrict__ x2, const float* __restrict__ x4,
    const float* __restrict__ invn1, const float* __restrict__ invn2,
    float* __restrict__ S, float* __restrict__ rowsum, float* __restrict__ colsum)
{
    const int b  = blockIdx.z;
    const int i0 = blockIdx.y * 64;
    const int j0 = blockIdx.x * 64;
    __shared__ float As[64][68];
    __shared__ float Bs[64][68];
    __shared__ float rsh[64], csh[64];
    const int t = threadIdx.x;
    const int tx = t & 15, ty = t >> 4;
    if (t < 64) { rsh[t] = 0.f; csh[t] = 0.f; }
    float acc[4][4] = {};
    const int lk = t & 63, r4 = t >> 6;
    for (int kc = 0; kc < DIM; kc += 64) {
        __syncthreads();
        #pragma unroll
        for (int rr = 0; rr < 64; rr += 4) {
            const int r = rr + r4;
            const int gi = i0 + r;
            const float* pa = (gi < NREAL) ? x1 + ((size_t)b * NREAL + gi) * DIM
                                           : x3 + ((size_t)b * NPAD + (gi - NREAL)) * DIM;
            As[r][lk] = pa[kc + lk] * invn1[b * NFULL + gi];
            const int gj = j0 + r;
            const float* pb = (gj < NREAL) ? x2 + ((size_t)b * NREAL + gj) * DIM
                                           : x4 + ((size_t)b * NPAD + (gj - NREAL)) * DIM;
            Bs[r][lk] = pb[kc + lk] * invn2[b * NFULL + gj];
        }
        __syncthreads();
        #pragma unroll
        for (int k = 0; k < 64; k += 4) {
            float4 av[4], bv[4];
            #pragma unroll
            for (int u = 0; u < 4; ++u) av[u] = *(const float4*)&As[ty + 16*u][k];
            #pragma unroll
            for (int u = 0; u < 4; ++u) bv[u] = *(const float4*)&Bs[tx + 16*u][k];
            #pragma unroll
            for (int u = 0; u < 4; ++u)
                #pragma unroll
                for (int v = 0; v < 4; ++v) {
                    acc[u][v] += av[u].x * bv[v].x;
                    acc[u][v] += av[u].y * bv[v].y;
                    acc[u][v] += av[u].z * bv[v].z;
                    acc[u][v] += av[u].w * bv[v].w;
                }
        }
    }
    float rpart[4] = {}, cpart[4] = {};
    const bool store = (i0 < NREAL) && (j0 < NREAL);
    #pragma unroll
    for (int u = 0; u < 4; ++u)
        #pragma unroll
        for (int v = 0; v < 4; ++v) {
            const float s = __expf(10.0f * acc[u][v]);
            rpart[u] += s;
            cpart[v] += s;
            if (store) {
                const int i = i0 + ty + 16*u, j = j0 + tx + 16*v;
                S[((size_t)b * NREAL + i) * NREAL + j] = s;
            }
        }
    #pragma unroll
    for (int u = 0; u < 4; ++u) atomicAdd(&rsh[ty + 16*u], rpart[u]);
    #pragma unroll
    for (int v = 0; v < 4; ++v) atomicAdd(&csh[tx + 16*v], cpart[v]);
    __syncthreads();
    if (t < 64) {
        atomicAdd(&rowsum[b * NFULL + i0 + t], rsh[t]);
        atomicAdd(&colsum[b * NFULL + j0 + t], csh[t]);
    }
}

__global__ __launch_bounds__(256) void hinge_kernel(
    const float* __restrict__ x3, const float* __restrict__ x4, float* __restrict__ out)
{
    const int b  = blockIdx.z;
    const int i0 = blockIdx.y * 64;
    const int j0 = blockIdx.x * 64;
    __shared__ float As[64][68];
    __shared__ float Bs[64][68];
    const int t = threadIdx.x;
    const int tx = t & 15, ty = t >> 4;
    float acc[4][4] = {};
    const int lk = t & 63, r4 = t >> 6;
    for (int kc = 0; kc < DIM; kc += 64) {
        __syncthreads();
        #pragma unroll
        for (int rr = 0; rr < 64; rr += 4) {
            const int r = rr + r4;
            As[r][lk] = x3[((size_t)b * NPAD + i0 + r) * DIM + kc + lk];
            Bs[r][lk] = x4[((size_t)b * NPAD + j0 + r) * DIM + kc + lk];
        }
        __syncthreads();
        #pragma unroll
        for (int k = 0; k < 64; k += 4) {
            float4 av[4], bv[4];
            #pragma unroll
            for (int u = 0; u < 4; ++u) av[u] = *(const float4*)&As[ty + 16*u][k];
            #pragma unroll
            for (int u = 0; u < 4; ++u) bv[u] = *(const float4*)&Bs[tx + 16*u][k];
            #pragma unroll
            for (int u = 0; u < 4; ++u)
                #pragma unroll
                for (int v = 0; v < 4; ++v) {
                    acc[u][v] += av[u].x * bv[v].x;
                    acc[u][v] += av[u].y * bv[v].y;
                    acc[u][v] += av[u].z * bv[v].z;
                    acc[u][v] += av[u].w * bv[v].w;
                }
        }
    }
    float part = 0.f;
    #pragma unroll
    for (int u = 0; u < 4; ++u)
        #pragma unroll
        for (int v = 0; v < 4; ++v) part += fmaxf(0.1f - acc[u][v], 0.f);
    __shared__ float red[256];
    red[t] = part;
    __syncthreads();
    for (int s = 128; s > 0; s >>= 1) { if (t < s) red[t] += red[t + s]; __syncthreads(); }
    if (t == 0) atomicAdd(out, red[0]);
}

// ---------------------------------------------------------------------------
// C = 1 - S/(rowsum_i + colsum_j - S) in place, plus optional transposed copy.
__global__ __launch_bounds__(256) void cost_kernel(
    float* __restrict__ C, float* __restrict__ CT,
    const float* __restrict__ rowsum, const float* __restrict__ colsum)
{
    const int b  = blockIdx.z;
    const int i0 = blockIdx.y * 64, j0 = blockIdx.x * 64;
    __shared__ float tile[64][65];
    const int t = threadIdx.x;
    const int lj = t & 63, r4 = t >> 6;
    #pragma unroll
    for (int rr = 0; rr < 64; rr += 4) {
        const int li = rr + r4;
        const size_t idx = ((size_t)b * NREAL + i0 + li) * NREAL + j0 + lj;
        const float s  = C[idx];
        const float rs = rowsum[b * NFULL + i0 + li];
        const float cs = colsum[b * NFULL + j0 + lj];
        const float c = 1.0f - s / (rs + cs - s);
        C[idx] = c;
        tile[li][lj] = c;
    }
    if (CT == nullptr) return;
    __syncthreads();
    #pragma unroll
    for (int rr = 0; rr < 4 * 16; rr += 4) {
        const int lc = rr + r4;
        CT[((size_t)b * NREAL + j0 + lc) * NREAL + i0 + lj] = tile[lj][lc];
    }
}

// ---------------------------------------------------------------------------
// Branchless two-pass softmin; one wave = 4 rows of one (side, b).
// All 8 row-loads (float4) issued before any use for max MLP.
// mode 0: write state. mode 1: 0.5*(old + new). mode 2: block-reduced
// atomicAdd(out, sum/B).
__global__ __launch_bounds__(256) void softmin_kernel(
    const float* __restrict__ C, const float* __restrict__ CT,
    const float* __restrict__ f_in, const float* __restrict__ g_in,
    float* __restrict__ f_out, float* __restrict__ g_out,
    float eps, int mode, float* __restrict__ out)
{
    const int w = threadIdx.x >> 6, lane = threadIdx.x & 63;
    const int rg = blockIdx.x * 4 + w;           // 0 .. 4095
    const int side = rg >= 2048;
    const int rem  = side ? rg - 2048 : rg;
    const int b  = rem >> 7;
    const int ib = (rem & 127) * 4;
    const float inv_eps = 1.0f / eps;
    const float* h_src = (side ? f_in : g_in) + b * NREAL;

    f32x4 h0 = {0.f, 0.f, 0.f, 0.f}, h1 = h0;
    if (mode != 0) {
        const f32x4* h4 = (const f32x4*)h_src;
        h0 = h4[lane] * inv_eps;
        h1 = h4[64 + lane] * inv_eps;
    }

    const float* Mb;
    size_t stride;
    if (!side)   { Mb = C  + ((size_t)(b * NREAL + ib)) * NREAL; stride = 1; }
    else if (CT) { Mb = CT + ((size_t)(b * NREAL + ib)) * NREAL; stride = 1; }
    else         { Mb = C + (size_t)b * NREAL * NREAL + ib;      stride = NREAL; }

    float res[4];
    float acc_res = 0.f;
    if (stride == 1) {
        f32x4 A0[4], A1[4];
        #pragma unroll
        for (int rr = 0; rr < 4; ++rr) {
            const f32x4* M4 = (const f32x4*)(Mb + (size_t)rr * NREAL);
            A0[rr] = M4[lane];
            A1[rr] = M4[64 + lane];
        }
        #pragma unroll
        for (int rr = 0; rr < 4; ++rr) {
            const f32x4 v0 = h0 - A0[rr] * inv_eps;
            const f32x4 v1 = h1 - A1[rr] * inv_eps;
            float mx = fmaxf(fmaxf(fmaxf(v0[0], v0[1]), fmaxf(v0[2], v0[3])),
                             fmaxf(fmaxf(v1[0], v1[1]), fmaxf(v1[2], v1[3])));
            #pragma unroll
            for (int off = 1; off < 64; off <<= 1) mx = fmaxf(mx, __shfl_xor(mx, off));
            float s = 0.f;
            #pragma unroll
            for (int c = 0; c < 4; ++c) s += __expf(v0[c] - mx);
            #pragma unroll
            for (int c = 0; c < 4; ++c) s += __expf(v1[c] - mx);
            #pragma unroll
            for (int off = 1; off < 64; off <<= 1) s += __shfl_xor(s, off);
            res[rr] = -eps * (mx + __logf(s));
            acc_res += res[rr];
        }
    } else {
        #pragma unroll
        for (int rr = 0; rr < 4; ++rr) {
            const float* M = Mb + rr;
            float v[8];
            #pragma unroll
            for (int q = 0; q < 8; ++q) {
                const float h = (q < 4) ? h0[q & 3] : h1[q & 3];
                v[q] = h - M[(size_t)((q & 3) + (q >> 2) * 256 + lane * 4) * NREAL
                             - (size_t)(lane * 4 + (q & 3) + (q >> 2) * 256) * 0] * inv_eps;
            }
            // strided fallback: element j = (q>>2)*256 + lane*4 + (q&3)
            #pragma unroll
            for (int q = 0; q < 8; ++q) {
                const int j = (q >> 2) * 256 + lane * 4 + (q & 3);
                v[q] = ((q < 4) ? h0[q & 3] : h1[q & 3]) - M[(size_t)j * NREAL] * inv_eps;
            }
            float mx = v[0];
            #pragma unroll
            for (int q = 1; q < 8; ++q) mx = fmaxf(mx, v[q]);
            #pragma unroll
            for (int off = 1; off < 64; off <<= 1) mx = fmaxf(mx, __shfl_xor(mx, off));
            float s = 0.f;
            #pragma unroll
            for (int q = 0; q < 8; ++q) s += __expf(v[q] - mx);
            #pragma unroll
            for (int off = 1; off < 64; off <<= 1) s += __shfl_xor(s, off);
            res[rr] = -eps * (mx + __logf(s));
            acc_res += res[rr];
        }
    }

    if (mode == 2) {
        __shared__ float sred[4];
        if (lane == 0) sred[w] = acc_res;
        __syncthreads();
        if (threadIdx.x == 0)
            atomicAdd(out, (sred[0] + sred[1] + sred[2] + sred[3]) * (1.0f / BATCH));
    } else if (lane == 0) {
        float* st = (side ? g_out : f_out) + b * NREAL + ib;
        if (mode == 0) {
            *(f32x4*)st = f32x4{res[0], res[1], res[2], res[3]};
        } else {
            const f32x4 si = *(const f32x4*)((side ? g_in : f_in) + b * NREAL + ib);
            *(f32x4*)st = 0.5f * (si + f32x4{res[0], res[1], res[2], res[3]});
        }
    }
}

// ---------------------------------------------------------------------------
extern "C" void kernel_launch(void* const* d_in, const int* in_sizes, int n_in,
                              void* d_out, int out_size, void* d_ws, size_t ws_size,
                              hipStream_t stream)
{
    const float* x1 = (const float*)d_in[0];
    const float* x2 = (const float*)d_in[1];
    const float* x3 = (const float*)d_in[2];
    const float* x4 = (const float*)d_in[3];
    float* out = (float*)d_out;

    char* p = (char*)d_ws;
    const size_t CBYTES = (size_t)BATCH * NREAL * NREAL * 4;  // 16.78 MB
    const size_t ABYTES = (size_t)BATCH * NFULL * 512 * 2;    // 14.68 MB
    const size_t NB = (size_t)BATCH * NFULL * 4;              // 57 KB
    const size_t PB = (size_t)BATCH * NREAL * 4;              // 32 KB
    const size_t SMALLB = 6 * NB + 4 * PB;
    const bool mfma_ok = ws_size >= CBYTES + 2 * ABYTES + SMALLB;

    float* C = (float*)p; p += CBYTES;
    short* A1s = nullptr; short* B2s = nullptr;
    float* CT = nullptr;
    if (mfma_ok) {
        A1s = (short*)p; p += ABYTES;
        B2s = (short*)p; p += ABYTES;
        CT = (float*)A1s;   // A/B planes dead after gram; cost reuses the region
    }
    float* rowsum = (float*)p; p += NB;
    float* colsum = (float*)p; p += NB;
    float* invn1  = (float*)p; p += NB;
    float* invn2  = (float*)p; p += NB;
    float* n1     = (float*)p; p += NB;
    float* n2     = (float*)p; p += NB;
    float* fs     = (float*)p; p += 2 * PB;
    float* gs     = (float*)p; p += 2 * PB;
    if (!mfma_ok && ws_size >= (size_t)(p - (char*)d_ws) + CBYTES) {
        CT = (float*)p; p += CBYTES;
    }
    const int PS = BATCH * NREAL;

    if (mfma_ok) {
        norm_cvt_kernel<<<(2 * BATCH * NFULL) / 4, 256, 0, stream>>>(
            x1, x3, x2, x4, A1s, B2s, invn1, invn2, n1, n2, rowsum, out);
        gram_mfma_kernel<<<784, 256, 0, stream>>>(
            A1s, B2s, n1, n2, C, rowsum, colsum, out);
    } else {
        hipMemsetAsync(out, 0, 2 * sizeof(float), stream);
        hipMemsetAsync(rowsum, 0, 2 * NB, stream);
        norm_kernel<<<(2 * BATCH * NFULL) / 4, 256, 0, stream>>>(
            x1, x3, x2, x4, invn1, invn2);
        gram_kernel<<<dim3(14, 14, BATCH), 256, 0, stream>>>(
            x1, x3, x2, x4, invn1, invn2, C, rowsum, colsum);
        hinge_kernel<<<dim3(6, 6, BATCH), 256, 0, stream>>>(x3, x4, out);
    }
    cost_kernel<<<dim3(8, 8, BATCH), 256, 0, stream>>>(C, CT, rowsum, colsum);

    const int SMB = 1024;
    const float epsl[8] = {9.0f, 9.0f, 2.25f, 0.5625f, 0.140625f,
                           0.03515625f, 0.0087890625f, 0.0025f};

    softmin_kernel<<<SMB, 256, 0, stream>>>(C, CT, fs, gs, fs, gs, 9.0f, 0, out);
    int cur = 0;
    for (int k = 0; k < 8; ++k) {
        softmin_kernel<<<SMB, 256, 0, stream>>>(C, CT,
            fs + cur * PS, gs + cur * PS,
            fs + (1 - cur) * PS, gs + (1 - cur) * PS,
            epsl[k], 1, out);
        cur ^= 1;
    }
    softmin_kernel<<<SMB, 256, 0, stream>>>(C, CT,
        fs + cur * PS, gs + cur * PS, nullptr, nullptr,
        0.0025f, 2, out + 1);
}